// Round 9
// baseline (300.843 us; speedup 1.0000x reference)
//
#include <hip/hip_runtime.h>
#include <math.h>

#define NROWS 16384
#define NCOLS 1000
#define NMAT  5
#define WPB   4                         // waves (rows) per block
#define GRIDX (NROWS / WPB)             // 4096 row-blocks per matrix
#define NBLOCKS (GRIDX * NMAT)          // 20480 blocks, 1-D, matrix-MAJOR

typedef float f4 __attribute__((ext_vector_type(4)));

// ---------------------------------------------------------------------------
// Kernel 1: one 64-lane wave per (row, matrix).
// Loads use sc0 (L1-bypass, NORMAL L2/L3 allocation) via inline asm.
// Measured history: normal loads cap at ~2.95 TB/s even when data is fully
// cache-resident (R7 warm dispatches) -> L1 allocation path is the limiter.
// nt-everywhere (L1+L2+L3 evict-first) fixed the kernel (55.5 us, 5.9 TB/s,
// R5/R8) but demoted the L3-resident input lines, costing ~30 us/iter in the
// harness's input-restore (overhead 183 -> 219 us, 4-run consistent).
// sc0 aims to keep the 2x L1-bypass win while leaving inputs L3-warm.
// Margin written directly to out[1 + row*5 + m]; matrices 0..3 feed a
// per-block max -> blockmax[] (64 KB of d_ws).
// ---------------------------------------------------------------------------
__global__ __launch_bounds__(256) void topk_kernel(
    const float* __restrict__ o0, const float* __restrict__ o1,
    const float* __restrict__ o2, const float* __restrict__ o3,
    const float* __restrict__ o4, const int* __restrict__ targets,
    float* __restrict__ out, float* __restrict__ blockmax)
{
    const int bid  = blockIdx.x;
    const int m    = bid / GRIDX;       // matrix-major (neutral; kept)
    const int xb   = bid % GRIDX;       // row-block 0..4095 within matrix
    const int wave = threadIdx.x >> 6;
    const int lane = threadIdx.x & 63;
    const int row  = xb * WPB + wave;

    const float* base = (m == 0) ? o0 : (m == 1) ? o1 : (m == 2) ? o2
                      : (m == 3) ? o3 : o4;
    const f4* b = (const f4*)(base + (size_t)row * NCOLS);

    const int t = targets[row];         // wave-uniform, issued early

    // 250 float4 per row: 3 full chunks + partial 4th (lanes 0..57; lanes
    // 58..63 load a clamped in-bounds address and are masked to -inf after).
    // One asm block: 4 loads issue back-to-back (MLP=4), one vmcnt(0);
    // consumers depend on asm outputs, so ordering is data-enforced.
    const f4* p  = b + lane;
    const f4* p3 = b + (lane < 58 ? lane + 192 : lane);
    f4 v0, v1, v2, v3;
    asm volatile(
        "global_load_dwordx4 %0, %4, off sc0\n\t"
        "global_load_dwordx4 %1, %4, off offset:1024 sc0\n\t"
        "global_load_dwordx4 %2, %4, off offset:2048 sc0\n\t"
        "global_load_dwordx4 %3, %5, off sc0\n\t"
        "s_waitcnt vmcnt(0)"
        : "=&v"(v0), "=&v"(v1), "=&v"(v2), "=&v"(v3)
        : "v"(p), "v"(p3)
        : "memory");
    const f4 NEG = { -INFINITY, -INFINITY, -INFINITY, -INFINITY };
    if (lane >= 58) v3 = NEG;

    // Per-lane top-2 (branch-free; duplicated max handled correctly).
    float t1 = -INFINITY, t2 = -INFINITY;
#define UPD(x) { float _mn = fminf(t1, (x)); t1 = fmaxf(t1, (x)); \
                 t2 = fmaxf(t2, _mn); }
    UPD(v0.x) UPD(v0.y) UPD(v0.z) UPD(v0.w)
    UPD(v1.x) UPD(v1.y) UPD(v1.z) UPD(v1.w)
    UPD(v2.x) UPD(v2.y) UPD(v2.z) UPD(v2.w)
    UPD(v3.x) UPD(v3.y) UPD(v3.z) UPD(v3.w)
#undef UPD

    // Target logit from registers: column t lives in f4 chunk (t>>2)>>6
    // of lane (t>>2)&63, component t&3. All wave-uniform.
    const int q = t >> 2, comp = t & 3, src = q & 63, chunk = q >> 6;
    f4 cv = (chunk == 0) ? v0 : (chunk == 1) ? v1 : (chunk == 2) ? v2 : v3;
    float cand = (comp == 0) ? cv.x : (comp == 1) ? cv.y
               : (comp == 2) ? cv.z : cv.w;
    const float tv = __shfl(cand, src);   // src <= 57 when chunk==3, so valid

    // 6-step butterfly top-2 reduction across the wave.
    #pragma unroll
    for (int off = 32; off > 0; off >>= 1) {
        float a1 = __shfl_xor(t1, off);
        float a2 = __shfl_xor(t2, off);
        float mn = fminf(t1, a1);
        t1 = fmaxf(t1, a1);
        t2 = fmaxf(fmaxf(t2, a2), mn);
    }

    // Raw margin -> out; tail_kernel rewrites these in place.
    if (lane == 0)
        out[1 + row * NMAT + m] = (tv == t1) ? (t1 - t2) : 0.0f;

    // Per-block max for matrices 0..3 (mimic excluded). m is block-uniform,
    // so the barrier is non-divergent.
    if (m < 4) {
        __shared__ float smax[WPB];
        if (lane == 0) smax[wave] = t1;
        __syncthreads();
        if (threadIdx.x == 0)
            blockmax[m * GRIDX + xb] =
                fmaxf(fmaxf(smax[0], smax[1]), fmaxf(smax[2], smax[3]));
    }
}

// ---------------------------------------------------------------------------
// Kernel 2 (merged tail): blocks 0..63 do the in-place per-row softmax over
// the 5 margins in out (T = 2.0); block 64 reduces the block maxima to
// out[0]. The two jobs touch disjoint data, both depend only on topk_kernel.
// ---------------------------------------------------------------------------
__global__ __launch_bounds__(256) void tail_kernel(
    const float* __restrict__ blockmax, float* __restrict__ out)
{
    if (blockIdx.x < 64) {
        const int i = blockIdx.x * 256 + threadIdx.x;   // 16384 rows
        float mg[NMAT];
        #pragma unroll
        for (int m = 0; m < NMAT; ++m) mg[m] = out[1 + i * NMAT + m];
        float mx = mg[0];
        #pragma unroll
        for (int m = 1; m < NMAT; ++m) mx = fmaxf(mx, mg[m]);
        float e[NMAT], s = 0.0f;
        #pragma unroll
        for (int m = 0; m < NMAT; ++m) { e[m] = __expf((mg[m] - mx) * 0.5f); s += e[m]; }
        const float inv = 1.0f / s;
        #pragma unroll
        for (int m = 0; m < NMAT; ++m) out[1 + i * NMAT + m] = e[m] * inv;
    } else {
        __shared__ float red[256];
        float mm = -INFINITY;
        for (int k = threadIdx.x; k < 4 * GRIDX; k += 256)
            mm = fmaxf(mm, blockmax[k]);
        red[threadIdx.x] = mm;
        __syncthreads();
        #pragma unroll
        for (int s = 128; s > 0; s >>= 1) {
            if (threadIdx.x < s)
                red[threadIdx.x] = fmaxf(red[threadIdx.x], red[threadIdx.x + s]);
            __syncthreads();
        }
        if (threadIdx.x == 0) out[0] = red[0];
    }
}

extern "C" void kernel_launch(void* const* d_in, const int* in_sizes, int n_in,
                              void* d_out, int out_size, void* d_ws, size_t ws_size,
                              hipStream_t stream) {
    const float* o0 = (const float*)d_in[0];
    const float* o1 = (const float*)d_in[1];
    const float* o2 = (const float*)d_in[2];
    const float* o3 = (const float*)d_in[3];
    const float* o4 = (const float*)d_in[4];
    const int*   tg = (const int*)d_in[5];
    float* out = (float*)d_out;

    float* blockmax = (float*)d_ws;                 // 4*4096 floats (64 KB)

    topk_kernel<<<NBLOCKS, 256, 0, stream>>>(
        o0, o1, o2, o3, o4, tg, out, blockmax);
    tail_kernel<<<65, 256, 0, stream>>>(blockmax, out);
}

// Round 10
// 298.433 us; speedup vs baseline: 1.0081x; 1.0081x over previous
//
#include <hip/hip_runtime.h>
#include <math.h>

#define NROWS 16384
#define NCOLS 1000
#define NMAT  5
#define WPB   4                         // waves (rows) per block
#define GRIDX (NROWS / WPB)             // 4096 row-blocks per matrix
#define NBLOCKS (GRIDX * NMAT)          // 20480 blocks, 1-D, matrix-MAJOR

typedef float f4 __attribute__((ext_vector_type(4)));

// ---------------------------------------------------------------------------
// Kernel 1: one 64-lane wave per (row, matrix).
// Load-flag ladder (measured): normal=111us, sc0=111us, nt=55.5us.
// The 2x lever is in the TCC/L2 request path, triggered by nt; but nt's
// all-level evict-first hint demotes the inputs' Infinity-Cache lines and
// costs ~30us/iter in the harness input-restore (overhead 190 -> 220).
// This round: sc0 sc1 = bypass L1 AND L2 allocation WITHOUT the nt
// replacement hint -- testing whether the fast path is "skip L2 alloc"
// (then MALL stays warm: kernel ~55us AND overhead ~190) or the nt hint
// itself (then 111us -> revert to R8's nt kernel, declare roofline).
// Margin written directly to out[1 + row*5 + m]; matrices 0..3 feed a
// per-block max -> blockmax[] (64 KB of d_ws).
// ---------------------------------------------------------------------------
__global__ __launch_bounds__(256) void topk_kernel(
    const float* __restrict__ o0, const float* __restrict__ o1,
    const float* __restrict__ o2, const float* __restrict__ o3,
    const float* __restrict__ o4, const int* __restrict__ targets,
    float* __restrict__ out, float* __restrict__ blockmax)
{
    const int bid  = blockIdx.x;
    const int m    = bid / GRIDX;       // matrix-major (neutral; kept)
    const int xb   = bid % GRIDX;       // row-block 0..4095 within matrix
    const int wave = threadIdx.x >> 6;
    const int lane = threadIdx.x & 63;
    const int row  = xb * WPB + wave;

    const float* base = (m == 0) ? o0 : (m == 1) ? o1 : (m == 2) ? o2
                      : (m == 3) ? o3 : o4;
    const f4* b = (const f4*)(base + (size_t)row * NCOLS);

    const int t = targets[row];         // wave-uniform, issued early

    // 250 float4 per row: 3 full chunks + partial 4th (lanes 0..57; lanes
    // 58..63 load a clamped in-bounds address and are masked to -inf after).
    // One asm block: 4 loads issue back-to-back (MLP=4), one vmcnt(0).
    const f4* p  = b + lane;
    const f4* p3 = b + (lane < 58 ? lane + 192 : lane);
    f4 v0, v1, v2, v3;
    asm volatile(
        "global_load_dwordx4 %0, %4, off sc0 sc1\n\t"
        "global_load_dwordx4 %1, %4, off offset:1024 sc0 sc1\n\t"
        "global_load_dwordx4 %2, %4, off offset:2048 sc0 sc1\n\t"
        "global_load_dwordx4 %3, %5, off sc0 sc1\n\t"
        "s_waitcnt vmcnt(0)"
        : "=&v"(v0), "=&v"(v1), "=&v"(v2), "=&v"(v3)
        : "v"(p), "v"(p3)
        : "memory");
    const f4 NEG = { -INFINITY, -INFINITY, -INFINITY, -INFINITY };
    if (lane >= 58) v3 = NEG;

    // Per-lane top-2 (branch-free; duplicated max handled correctly).
    float t1 = -INFINITY, t2 = -INFINITY;
#define UPD(x) { float _mn = fminf(t1, (x)); t1 = fmaxf(t1, (x)); \
                 t2 = fmaxf(t2, _mn); }
    UPD(v0.x) UPD(v0.y) UPD(v0.z) UPD(v0.w)
    UPD(v1.x) UPD(v1.y) UPD(v1.z) UPD(v1.w)
    UPD(v2.x) UPD(v2.y) UPD(v2.z) UPD(v2.w)
    UPD(v3.x) UPD(v3.y) UPD(v3.z) UPD(v3.w)
#undef UPD

    // Target logit from registers: column t lives in f4 chunk (t>>2)>>6
    // of lane (t>>2)&63, component t&3. All wave-uniform.
    const int q = t >> 2, comp = t & 3, src = q & 63, chunk = q >> 6;
    f4 cv = (chunk == 0) ? v0 : (chunk == 1) ? v1 : (chunk == 2) ? v2 : v3;
    float cand = (comp == 0) ? cv.x : (comp == 1) ? cv.y
               : (comp == 2) ? cv.z : cv.w;
    const float tv = __shfl(cand, src);   // src <= 57 when chunk==3, so valid

    // 6-step butterfly top-2 reduction across the wave.
    #pragma unroll
    for (int off = 32; off > 0; off >>= 1) {
        float a1 = __shfl_xor(t1, off);
        float a2 = __shfl_xor(t2, off);
        float mn = fminf(t1, a1);
        t1 = fmaxf(t1, a1);
        t2 = fmaxf(fmaxf(t2, a2), mn);
    }

    // Raw margin -> out; tail_kernel rewrites these in place.
    if (lane == 0)
        out[1 + row * NMAT + m] = (tv == t1) ? (t1 - t2) : 0.0f;

    // Per-block max for matrices 0..3 (mimic excluded). m is block-uniform,
    // so the barrier is non-divergent.
    if (m < 4) {
        __shared__ float smax[WPB];
        if (lane == 0) smax[wave] = t1;
        __syncthreads();
        if (threadIdx.x == 0)
            blockmax[m * GRIDX + xb] =
                fmaxf(fmaxf(smax[0], smax[1]), fmaxf(smax[2], smax[3]));
    }
}

// ---------------------------------------------------------------------------
// Kernel 2 (merged tail): blocks 0..63 do the in-place per-row softmax over
// the 5 margins in out (T = 2.0); block 64 reduces the block maxima to
// out[0]. The two jobs touch disjoint data, both depend only on topk_kernel.
// ---------------------------------------------------------------------------
__global__ __launch_bounds__(256) void tail_kernel(
    const float* __restrict__ blockmax, float* __restrict__ out)
{
    if (blockIdx.x < 64) {
        const int i = blockIdx.x * 256 + threadIdx.x;   // 16384 rows
        float mg[NMAT];
        #pragma unroll
        for (int m = 0; m < NMAT; ++m) mg[m] = out[1 + i * NMAT + m];
        float mx = mg[0];
        #pragma unroll
        for (int m = 1; m < NMAT; ++m) mx = fmaxf(mx, mg[m]);
        float e[NMAT], s = 0.0f;
        #pragma unroll
        for (int m = 0; m < NMAT; ++m) { e[m] = __expf((mg[m] - mx) * 0.5f); s += e[m]; }
        const float inv = 1.0f / s;
        #pragma unroll
        for (int m = 0; m < NMAT; ++m) out[1 + i * NMAT + m] = e[m] * inv;
    } else {
        __shared__ float red[256];
        float mm = -INFINITY;
        for (int k = threadIdx.x; k < 4 * GRIDX; k += 256)
            mm = fmaxf(mm, blockmax[k]);
        red[threadIdx.x] = mm;
        __syncthreads();
        #pragma unroll
        for (int s = 128; s > 0; s >>= 1) {
            if (threadIdx.x < s)
                red[threadIdx.x] = fmaxf(red[threadIdx.x], red[threadIdx.x + s]);
            __syncthreads();
        }
        if (threadIdx.x == 0) out[0] = red[0];
    }
}

extern "C" void kernel_launch(void* const* d_in, const int* in_sizes, int n_in,
                              void* d_out, int out_size, void* d_ws, size_t ws_size,
                              hipStream_t stream) {
    const float* o0 = (const float*)d_in[0];
    const float* o1 = (const float*)d_in[1];
    const float* o2 = (const float*)d_in[2];
    const float* o3 = (const float*)d_in[3];
    const float* o4 = (const float*)d_in[4];
    const int*   tg = (const int*)d_in[5];
    float* out = (float*)d_out;

    float* blockmax = (float*)d_ws;                 // 4*4096 floats (64 KB)

    topk_kernel<<<NBLOCKS, 256, 0, stream>>>(
        o0, o1, o2, o3, o4, tg, out, blockmax);
    tail_kernel<<<65, 256, 0, stream>>>(blockmax, out);
}

// Round 12
// 274.106 us; speedup vs baseline: 1.0975x; 1.0887x over previous
//
#include <hip/hip_runtime.h>
#include <math.h>

#define NROWS 16384
#define NCOLS 1000
#define NMAT  5
#define WPB   4                         // waves (rows) per block
#define GRIDX (NROWS / WPB)             // 4096 row-blocks per matrix
#define NBLOCKS (GRIDX * NMAT)          // 20480 blocks, 1-D, matrix-MAJOR

typedef float f4 __attribute__((ext_vector_type(4)));

// ---------------------------------------------------------------------------
// Kernel 1: one 64-lane wave per (row, matrix).
// ALL logit loads are non-temporal. Completed flag ladder (measured A/B):
//   normal = 111us | sc0 = 111us | sc0 sc1 = 111us | nt = 55.5us.
// Only the nt replacement/streaming hint unlocks the TCC fast path; coherent
// bypass (sc0/sc1) at any level is a null. R7's warm dispatches (~0 HBM
// traffic, same 111us) prove the normal-path cap (~2.95 TB/s) is a request-
// handling limit, not DRAM. With nt: 5.9 TB/s delivered = 94% of the
// 6.29 TB/s chip streaming ceiling (mixed L3+HBM tiers), FETCH+L3 hits
// exactly equal the 327.7 MB working set (zero redundant bytes).
// nt's ~30us harness-restore cost (MALL demotion) is inseparable from the
// fast path and net-positive: end-to-end 274 vs 298-301 for all non-nt.
// Margin written directly to out[1 + row*5 + m]; matrices 0..3 feed a
// per-block max -> blockmax[] (64 KB of d_ws).
// ---------------------------------------------------------------------------
__global__ __launch_bounds__(256) void topk_kernel(
    const float* __restrict__ o0, const float* __restrict__ o1,
    const float* __restrict__ o2, const float* __restrict__ o3,
    const float* __restrict__ o4, const int* __restrict__ targets,
    float* __restrict__ out, float* __restrict__ blockmax)
{
    const int bid  = blockIdx.x;
    const int m    = bid / GRIDX;       // matrix-major (neutral; kept)
    const int xb   = bid % GRIDX;       // row-block 0..4095 within matrix
    const int wave = threadIdx.x >> 6;
    const int lane = threadIdx.x & 63;
    const int row  = xb * WPB + wave;

    const float* base = (m == 0) ? o0 : (m == 1) ? o1 : (m == 2) ? o2
                      : (m == 3) ? o3 : o4;
    const f4* b = (const f4*)(base + (size_t)row * NCOLS);

    const int t = targets[row];         // wave-uniform, issued early

    // 250 float4 per row: 3 full chunks + partial 4th (lanes 0..57).
    // All non-temporal: the measured 2x lever.
    const f4 NEG = { -INFINITY, -INFINITY, -INFINITY, -INFINITY };
    f4 v0 = __builtin_nontemporal_load(b + lane);
    f4 v1 = __builtin_nontemporal_load(b + lane + 64);
    f4 v2 = __builtin_nontemporal_load(b + lane + 128);
    f4 v3 = (lane < 58) ? __builtin_nontemporal_load(b + lane + 192) : NEG;

    // Per-lane top-2 (branch-free; duplicated max handled correctly).
    float t1 = -INFINITY, t2 = -INFINITY;
#define UPD(x) { float _mn = fminf(t1, (x)); t1 = fmaxf(t1, (x)); \
                 t2 = fmaxf(t2, _mn); }
    UPD(v0.x) UPD(v0.y) UPD(v0.z) UPD(v0.w)
    UPD(v1.x) UPD(v1.y) UPD(v1.z) UPD(v1.w)
    UPD(v2.x) UPD(v2.y) UPD(v2.z) UPD(v2.w)
    UPD(v3.x) UPD(v3.y) UPD(v3.z) UPD(v3.w)
#undef UPD

    // Target logit from registers: column t lives in f4 chunk (t>>2)>>6
    // of lane (t>>2)&63, component t&3. All wave-uniform.
    const int q = t >> 2, comp = t & 3, src = q & 63, chunk = q >> 6;
    f4 cv = (chunk == 0) ? v0 : (chunk == 1) ? v1 : (chunk == 2) ? v2 : v3;
    float cand = (comp == 0) ? cv.x : (comp == 1) ? cv.y
               : (comp == 2) ? cv.z : cv.w;
    const float tv = __shfl(cand, src);   // src <= 57 when chunk==3, so valid

    // 6-step butterfly top-2 reduction across the wave.
    #pragma unroll
    for (int off = 32; off > 0; off >>= 1) {
        float a1 = __shfl_xor(t1, off);
        float a2 = __shfl_xor(t2, off);
        float mn = fminf(t1, a1);
        t1 = fmaxf(t1, a1);
        t2 = fmaxf(fmaxf(t2, a2), mn);
    }

    // Raw margin -> out; tail_kernel rewrites these in place.
    if (lane == 0)
        out[1 + row * NMAT + m] = (tv == t1) ? (t1 - t2) : 0.0f;

    // Per-block max for matrices 0..3 (mimic excluded). m is block-uniform,
    // so the barrier is non-divergent.
    if (m < 4) {
        __shared__ float smax[WPB];
        if (lane == 0) smax[wave] = t1;
        __syncthreads();
        if (threadIdx.x == 0)
            blockmax[m * GRIDX + xb] =
                fmaxf(fmaxf(smax[0], smax[1]), fmaxf(smax[2], smax[3]));
    }
}

// ---------------------------------------------------------------------------
// Kernel 2 (merged tail): blocks 0..63 do the in-place per-row softmax over
// the 5 margins in out (T = 2.0); block 64 reduces the block maxima to
// out[0]. The two jobs touch disjoint data, both depend only on topk_kernel.
// ---------------------------------------------------------------------------
__global__ __launch_bounds__(256) void tail_kernel(
    const float* __restrict__ blockmax, float* __restrict__ out)
{
    if (blockIdx.x < 64) {
        const int i = blockIdx.x * 256 + threadIdx.x;   // 16384 rows
        float mg[NMAT];
        #pragma unroll
        for (int m = 0; m < NMAT; ++m) mg[m] = out[1 + i * NMAT + m];
        float mx = mg[0];
        #pragma unroll
        for (int m = 1; m < NMAT; ++m) mx = fmaxf(mx, mg[m]);
        float e[NMAT], s = 0.0f;
        #pragma unroll
        for (int m = 0; m < NMAT; ++m) { e[m] = __expf((mg[m] - mx) * 0.5f); s += e[m]; }
        const float inv = 1.0f / s;
        #pragma unroll
        for (int m = 0; m < NMAT; ++m) out[1 + i * NMAT + m] = e[m] * inv;
    } else {
        __shared__ float red[256];
        float mm = -INFINITY;
        for (int k = threadIdx.x; k < 4 * GRIDX; k += 256)
            mm = fmaxf(mm, blockmax[k]);
        red[threadIdx.x] = mm;
        __syncthreads();
        #pragma unroll
        for (int s = 128; s > 0; s >>= 1) {
            if (threadIdx.x < s)
                red[threadIdx.x] = fmaxf(red[threadIdx.x], red[threadIdx.x + s]);
            __syncthreads();
        }
        if (threadIdx.x == 0) out[0] = red[0];
    }
}

extern "C" void kernel_launch(void* const* d_in, const int* in_sizes, int n_in,
                              void* d_out, int out_size, void* d_ws, size_t ws_size,
                              hipStream_t stream) {
    const float* o0 = (const float*)d_in[0];
    const float* o1 = (const float*)d_in[1];
    const float* o2 = (const float*)d_in[2];
    const float* o3 = (const float*)d_in[3];
    const float* o4 = (const float*)d_in[4];
    const int*   tg = (const int*)d_in[5];
    float* out = (float*)d_out;

    float* blockmax = (float*)d_ws;                 // 4*4096 floats (64 KB)

    topk_kernel<<<NBLOCKS, 256, 0, stream>>>(
        o0, o1, o2, o3, o4, tg, out, blockmax);
    tail_kernel<<<65, 256, 0, stream>>>(blockmax, out);
}